// Round 3
// baseline (143.071 us; speedup 1.0000x reference)
//
#include <hip/hip_runtime.h>
#include <math.h>

// Problem constants: B=64, K=1000, NPC=256, D=768, k=16, S=10
#define BQ   64
#define KC   1000
#define NPC  256
#define DIM  768
#define TOPK 16
#define NS   10

#define NEG_INF (-__builtin_inff())

#define DOT12(acc, A, Bv) \
    acc = fmaf(A.x, Bv.x, acc); acc = fmaf(A.y, Bv.y, acc); \
    acc = fmaf(A.z, Bv.z, acc); acc = fmaf(A.w, Bv.w, acc);

// ---------- Kernel A: normalize queries -> qn ; blocks 0..3 also zero cnt[] ----------
__global__ void knorm_q(const float* __restrict__ q, float* __restrict__ qn,
                        int* __restrict__ cnt) {
    int b = blockIdx.x, t = threadIdx.x;
    if (b < 4 && t < 250) cnt[b * 250 + t] = 0;
    const float* row = q + b * DIM;
    float v0 = row[t], v1 = row[t + 256], v2 = row[t + 512];
    __shared__ float red[256];
    red[t] = v0 * v0 + v1 * v1 + v2 * v2;
    __syncthreads();
    for (int off = 128; off; off >>= 1) {
        if (t < off) red[t] += red[t + off];
        __syncthreads();
    }
    float scale = 1.0f / fmaxf(sqrtf(red[0]), 1e-12f);
    qn[b * DIM + t]       = v0 * scale;
    qn[b * DIM + t + 256] = v1 * scale;
    qn[b * DIM + t + 512] = v2 * scale;
}

// ---------- Kernel B: cos_c[b][k] = dot(qn[b], centers[k]) / |centers[k]| ----------
__global__ void kcenter_scores(const float* __restrict__ qn,
                               const float* __restrict__ centers,
                               float* __restrict__ cosc) {
    int wave = threadIdx.x >> 6, lane = threadIdx.x & 63;
    int cblk = blockIdx.x >> 2, qg = blockIdx.x & 3;
    int k0 = cblk * 4 + wave;                    // 250*4 = 1000 exactly
    const float4* cp = (const float4*)(centers + (size_t)k0 * DIM);
    float4 c0 = cp[lane], c1 = cp[lane + 64], c2 = cp[lane + 128];
    float sq = 0.f;
    DOT12(sq, c0, c0); DOT12(sq, c1, c1); DOT12(sq, c2, c2);
    for (int off = 1; off < 64; off <<= 1) sq += __shfl_xor(sq, off);
    float inv = 1.0f / fmaxf(sqrtf(sq), 1e-12f);
    int b0 = qg * 16;
    for (int i = 0; i < 16; i += 4) {
        const float4* qa = (const float4*)(qn + (size_t)(b0 + i + 0) * DIM);
        const float4* qb = (const float4*)(qn + (size_t)(b0 + i + 1) * DIM);
        const float4* qc = (const float4*)(qn + (size_t)(b0 + i + 2) * DIM);
        const float4* qd = (const float4*)(qn + (size_t)(b0 + i + 3) * DIM);
        float4 a0 = qa[lane], a1 = qa[lane + 64], a2 = qa[lane + 128];
        float4 e0 = qb[lane], e1 = qb[lane + 64], e2 = qb[lane + 128];
        float4 f0 = qc[lane], f1 = qc[lane + 64], f2 = qc[lane + 128];
        float4 g0 = qd[lane], g1 = qd[lane + 64], g2 = qd[lane + 128];
        float dA = 0.f, dB = 0.f, dC = 0.f, dD = 0.f;
        DOT12(dA, a0, c0); DOT12(dA, a1, c1); DOT12(dA, a2, c2);
        DOT12(dB, e0, c0); DOT12(dB, e1, c1); DOT12(dB, e2, c2);
        DOT12(dC, f0, c0); DOT12(dC, f1, c1); DOT12(dC, f2, c2);
        DOT12(dD, g0, c0); DOT12(dD, g1, c1); DOT12(dD, g2, c2);
        for (int off = 1; off < 64; off <<= 1) {
            dA += __shfl_xor(dA, off);
            dB += __shfl_xor(dB, off);
            dC += __shfl_xor(dC, off);
            dD += __shfl_xor(dD, off);
        }
        if (lane == 0) {
            cosc[(b0 + i + 0) * KC + k0] = dA * inv;
            cosc[(b0 + i + 1) * KC + k0] = dB * inv;
            cosc[(b0 + i + 2) * KC + k0] = dC * inv;
            cosc[(b0 + i + 3) * KC + k0] = dD * inv;
        }
    }
}

// ---------- wave argmax: ties -> smaller index (matches jax.lax.top_k) ----------
__device__ __forceinline__ void wave_argmax(float& bv, int& bi) {
    for (int off = 1; off < 64; off <<= 1) {
        float v2 = __shfl_xor(bv, off);
        int   i2 = __shfl_xor(bi, off);
        if (v2 > bv || (v2 == bv && i2 < bi)) { bv = v2; bi = i2; }
    }
}

// ---------- Kernel C: per-query top-NS clusters + build inverted cluster->selector map ----------
__global__ void ktop_clusters(const float* __restrict__ cosc, int* __restrict__ cidx,
                              int* __restrict__ cnt, int* __restrict__ sel) {
    int b = blockIdx.x, t = threadIdx.x;
    int wave = t >> 6, lane = t & 63;
    __shared__ float vals[KC];
    __shared__ float wrv[4];
    __shared__ int   wri[4];
    for (int i = t; i < KC; i += 256) vals[i] = cosc[b * KC + i];
    __syncthreads();
    for (int s = 0; s < NS; ++s) {
        float bv = NEG_INF; int bi = 0x7fffffff;
        for (int i = t; i < KC; i += 256) {
            float v = vals[i];
            if (v > bv) { bv = v; bi = i; }
        }
        wave_argmax(bv, bi);
        if (lane == 0) { wrv[wave] = bv; wri[wave] = bi; }
        __syncthreads();
        if (t == 0) {
            float fv = wrv[0]; int fi = wri[0];
            for (int w = 1; w < 4; ++w) {
                float v2 = wrv[w]; int i2 = wri[w];
                if (v2 > fv || (v2 == fv && i2 < fi)) { fv = v2; fi = i2; }
            }
            cidx[b * NS + s] = fi;
            int pos = atomicAdd(&cnt[fi], 1);     // device-scope
            sel[fi * 64 + pos] = b * NS + s;      // append selector (order-independent use)
            vals[fi] = NEG_INF;
        }
        __syncthreads();
    }
}

// ---------- Kernel D: dedup'd candidate cosines ----------
// grid = KC*4 blocks x 256 threads. Block (c,sub) owns 64 docs of cluster c;
// exits if cluster unselected. Doc norms computed ONCE; dots per selector.
__global__ void kcand(const float* __restrict__ qn, const float* __restrict__ data,
                      const int* __restrict__ cnt, const int* __restrict__ sel,
                      float* __restrict__ cosall) {
    int c = blockIdx.x >> 2, sub = blockIdx.x & 3;
    int m = cnt[c];
    if (m == 0) return;
    int t = threadIdx.x;
    __shared__ int slist[64];
    if (t < m) slist[t] = sel[c * 64 + t];
    __syncthreads();
    int wave = t >> 6, lane = t & 63;
    const float* base = data + (size_t)c * NPC * DIM;
    int n0 = sub * 64 + wave * 16;
    for (int it = 0; it < 4; ++it) {
        int n = n0 + it * 4;
        const float4* dpa = (const float4*)(base + (size_t)(n + 0) * DIM);
        const float4* dpb = (const float4*)(base + (size_t)(n + 1) * DIM);
        const float4* dpc = (const float4*)(base + (size_t)(n + 2) * DIM);
        const float4* dpd = (const float4*)(base + (size_t)(n + 3) * DIM);
        float4 a0 = dpa[lane], a1 = dpa[lane + 64], a2 = dpa[lane + 128];
        float4 e0 = dpb[lane], e1 = dpb[lane + 64], e2 = dpb[lane + 128];
        float4 f0 = dpc[lane], f1 = dpc[lane + 64], f2 = dpc[lane + 128];
        float4 g0 = dpd[lane], g1 = dpd[lane + 64], g2 = dpd[lane + 128];
        float sqA = 0.f, sqB = 0.f, sqC = 0.f, sqD = 0.f;
        DOT12(sqA, a0, a0); DOT12(sqA, a1, a1); DOT12(sqA, a2, a2);
        DOT12(sqB, e0, e0); DOT12(sqB, e1, e1); DOT12(sqB, e2, e2);
        DOT12(sqC, f0, f0); DOT12(sqC, f1, f1); DOT12(sqC, f2, f2);
        DOT12(sqD, g0, g0); DOT12(sqD, g1, g1); DOT12(sqD, g2, g2);
        for (int off = 1; off < 64; off <<= 1) {
            sqA += __shfl_xor(sqA, off); sqB += __shfl_xor(sqB, off);
            sqC += __shfl_xor(sqC, off); sqD += __shfl_xor(sqD, off);
        }
        float invA = 1.0f / fmaxf(sqrtf(sqA), 1e-12f);
        float invB = 1.0f / fmaxf(sqrtf(sqB), 1e-12f);
        float invC = 1.0f / fmaxf(sqrtf(sqC), 1e-12f);
        float invD = 1.0f / fmaxf(sqrtf(sqD), 1e-12f);
        for (int j = 0; j < m; ++j) {
            int i = slist[j];
            int b = i / NS;
            const float4* qp = (const float4*)(qn + (size_t)b * DIM);
            float4 q0 = qp[lane], q1 = qp[lane + 64], q2 = qp[lane + 128];
            float dA = 0.f, dB = 0.f, dC = 0.f, dD = 0.f;
            DOT12(dA, q0, a0); DOT12(dA, q1, a1); DOT12(dA, q2, a2);
            DOT12(dB, q0, e0); DOT12(dB, q1, e1); DOT12(dB, q2, e2);
            DOT12(dC, q0, f0); DOT12(dC, q1, f1); DOT12(dC, q2, f2);
            DOT12(dD, q0, g0); DOT12(dD, q1, g1); DOT12(dD, q2, g2);
            for (int off = 1; off < 64; off <<= 1) {
                dA += __shfl_xor(dA, off); dB += __shfl_xor(dB, off);
                dC += __shfl_xor(dC, off); dD += __shfl_xor(dD, off);
            }
            if (lane == 0) {
                float* outp = cosall + (size_t)i * NPC + n;
                outp[0] = dA * invA;
                outp[1] = dB * invB;
                outp[2] = dC * invC;
                outp[3] = dD * invD;
            }
        }
    }
}

// ---------- Kernel E: per-query top-K + id write + embedding gather ----------
__global__ void ktop_final(const float* __restrict__ cosall, const int* __restrict__ cidx,
                           const int* __restrict__ clusted, const float* __restrict__ data,
                           float* __restrict__ out) {
    int b = blockIdx.x, t = threadIdx.x;
    int wave = t >> 6, lane = t & 63;
    __shared__ float vals[NS * NPC];
    __shared__ float wrv[4];
    __shared__ int   wri[4];
    __shared__ int   docs[TOPK];
    for (int i = t; i < NS * NPC; i += 256) vals[i] = cosall[(size_t)b * (NS * NPC) + i];
    __syncthreads();
    for (int j = 0; j < TOPK; ++j) {
        float bv = NEG_INF; int bi = 0x7fffffff;
        for (int i = t; i < NS * NPC; i += 256) {
            float v = vals[i];
            if (v > bv) { bv = v; bi = i; }
        }
        wave_argmax(bv, bi);
        if (lane == 0) { wrv[wave] = bv; wri[wave] = bi; }
        __syncthreads();
        if (t == 0) {
            float fv = wrv[0]; int fi = wri[0];
            for (int w = 1; w < 4; ++w) {
                float v2 = wrv[w]; int i2 = wri[w];
                if (v2 > fv || (v2 == fv && i2 < fi)) { fv = v2; fi = i2; }
            }
            int s = fi >> 8, n = fi & (NPC - 1);
            int c = cidx[b * NS + s];
            int doc = c * NPC + n;
            docs[j] = doc;
            out[b * TOPK + j] = (float)clusted[doc];   // ids < 2^24, exact in f32
            vals[fi] = NEG_INF;
        }
        __syncthreads();
    }
    float* emb = out + BQ * TOPK;
    for (int idx = t; idx < TOPK * (DIM / 4); idx += 256) {
        int j = idx / (DIM / 4), col = idx - j * (DIM / 4);
        int doc = docs[j];
        ((float4*)(emb + ((size_t)(b * TOPK + j)) * DIM))[col] =
            ((const float4*)(data + (size_t)doc * DIM))[col];
    }
}

extern "C" void kernel_launch(void* const* d_in, const int* in_sizes, int n_in,
                              void* d_out, int out_size, void* d_ws, size_t ws_size,
                              hipStream_t stream) {
    const float* querys  = (const float*)d_in[0];   // (64, 768)
    const float* data    = (const float*)d_in[1];   // (1000, 256, 768)
    const float* centers = (const float*)d_in[2];   // (1000, 768)
    const int*   clusted = (const int*)d_in[3];     // (1000, 256)
    float* out = (float*)d_out;                     // [64*16 ids as float][64*16*768 emb]

    float* ws     = (float*)d_ws;
    float* qn     = ws;                              // 64*768
    float* cosc   = qn + BQ * DIM;                   // 64*1000
    int*   cidx   = (int*)(cosc + BQ * KC);          // 64*10
    float* cosall = (float*)(cidx + BQ * NS);        // 64*2560
    int*   cnt    = (int*)(cosall + BQ * NS * NPC);  // 1000
    int*   sel    = cnt + KC;                        // 1000*64

    knorm_q<<<BQ, 256, 0, stream>>>(querys, qn, cnt);
    kcenter_scores<<<KC, 256, 0, stream>>>(qn, centers, cosc);
    ktop_clusters<<<BQ, 256, 0, stream>>>(cosc, cidx, cnt, sel);
    kcand<<<KC * 4, 256, 0, stream>>>(qn, data, cnt, sel, cosall);
    ktop_final<<<BQ, 256, 0, stream>>>(cosall, cidx, clusted, data, out);
}